// Round 1
// 242.781 us; speedup vs baseline: 1.0025x; 1.0025x over previous
//
#include <hip/hip_runtime.h>

// Problem constants (from reference setup_inputs):
//   x: (1, 3, 128, 128) fp32
//   w: (3, 124, 124, 25, 5, 5) fp32
//   q: (3, 124, 124, 25, 5, 5) fp32
//   out: (1, 3, 124, 124, 25) fp32
// out[o] = log( prod_{k=0..24} (1.1 + atan(10*(x_k*w_k - q_k))/pi) )
//
// R4 design: global_load_lds staging for w/q.
// R3 post-mortem: VGPR_Count=36 proved the "14 upfront register loads" were
// sunk by the register allocator (75 live floats can't fit 36 VGPRs) ->
// ~2-4 outstanding loads/wave, latency-bound. Additionally each lane-strided
// (100 B/lane) dwordx4 scatters 64 lanes over ~100 cache lines (~4-6x the
// line-request rate of a contiguous access) -> TA/L1 request-bound at 1.8 TB/s.
// Here: each block stages its 256 outputs' w/q (2 x 25.6 KB) via 14
// fire-and-forget global_load_lds_dwordx4 (per-instruction CONTIGUOUS: lane l
// reads base+16l -> 16 line-requests/instr, zero splits; no VGPR pressure, so
// nothing can be sunk). 3 blocks/CU -> ~150 KB in flight/CU >> BW*latency.
// Compute reads LDS at float-stride 25 (odd) -> 2 lanes/bank = free.
// x stays in registers: 25-lane groups share addresses, TA merges to ~3
// requests/instr, L1/L2-resident.

#define IMG   128
#define OUT   124
#define NUM   25
#define NPATCH (3 * OUT * OUT)
#define NOUT  (NPATCH * NUM)               // 1,153,200 outputs
#define OPB   256                          // outputs (= threads) per block

// Minimax atan, |err| ~ 2e-6 over all inputs. Range-reduce with v_rcp_f32.
__device__ __forceinline__ float fast_atan(float z) {
    float az  = __builtin_fabsf(z);
    float r   = __builtin_amdgcn_rcpf(az);
    bool  big = az > 1.0f;
    float t   = big ? r : az;                   // t in [0, 1]
    float s   = t * t;
    float p   =                     -0.01172120f;
    p = __builtin_fmaf(p, s,         0.05265332f);
    p = __builtin_fmaf(p, s,        -0.11643287f);
    p = __builtin_fmaf(p, s,         0.19354346f);
    p = __builtin_fmaf(p, s,        -0.33262347f);
    p = __builtin_fmaf(p, s,         0.99997726f);
    float a = t * p;
    a = big ? (1.57079632679489662f - a) : a;
    return __builtin_copysignf(a, z);
}

// Async global->LDS, 16 B per lane. LDS dest is wave-uniform base + lane*16
// (hardware semantics); global src is per-lane. Both 16B-aligned here.
__device__ __forceinline__ void copy16_lds(float* l, const float* g) {
    __builtin_amdgcn_global_load_lds(
        (const __attribute__((address_space(1))) unsigned int*)g,
        (__attribute__((address_space(3))) unsigned int*)l,
        16 /*bytes (literal)*/, 0 /*offset*/, 0 /*aux*/);
}

__global__ __launch_bounds__(OPB) void dendrite_kernel(
    const float* __restrict__ x,
    const float* __restrict__ w,
    const float* __restrict__ q,
    float* __restrict__ out)
{
    __shared__ float w_lds[OPB * NUM];     // 6400 floats = 25.6 KB
    __shared__ float q_lds[OPB * NUM];     // 6400 floats = 25.6 KB

    const int tid = threadIdx.x;
    const int wvb = tid & ~63;             // wave-uniform lane base
    const long long o_base = (long long)blockIdx.x * OPB;
    const int nrem = min(OPB, (int)(NOUT - o_base));   // 256, last block 176
    const int lim4 = (nrem * NUM) >> 2;    // float4 chunks to stage (1600/1100)

    const float* wsrc = w + o_base * NUM;
    const float* qsrc = q + o_base * NUM;

    // ---- Stage w, q: 7+7 contiguous fire-and-forget rounds, no waits ----
    #pragma unroll
    for (int r = 0; r < 7; ++r) {
        const int idx4 = r * OPB + tid;
        if (idx4 < lim4)
            copy16_lds(&w_lds[(r * OPB + wvb) * 4], wsrc + idx4 * 4);
    }
    #pragma unroll
    for (int r = 0; r < 7; ++r) {
        const int idx4 = r * OPB + tid;
        if (idx4 < lim4)
            copy16_lds(&q_lds[(r * OPB + wvb) * 4], qsrc + idx4 * 4);
    }

    // ---- x patch -> registers, overlapped with the staging flight ----
    const int o  = (int)o_base + tid;
    const int oc = min(o, NOUT - 1);       // clamp tail threads' addressing
    int rem = oc / NUM;                    // (c*OUT + i)*OUT + j
    const int j = rem % OUT;  rem /= OUT;
    const int i = rem % OUT;
    const int c = rem / OUT;
    const float* xp = x + ((long long)c * IMG + i) * IMG + j;

    float xv[NUM];
    #pragma unroll
    for (int u = 0; u < 5; ++u) {
        float4 a;
        __builtin_memcpy(&a, xp + u * IMG, sizeof(float4)); // dword-aligned ok
        xv[5*u+0] = a.x; xv[5*u+1] = a.y; xv[5*u+2] = a.z; xv[5*u+3] = a.w;
        xv[5*u+4] = xp[u * IMG + 4];
    }

    // Drain the global_load_lds queue once, then make LDS visible block-wide.
    asm volatile("s_waitcnt vmcnt(0)" ::: "memory");
    __syncthreads();

    // ---- Pure VALU epilogue: LDS reads at odd stride 25 (conflict-free) ----
    if (tid < nrem) {
        const float* wl = &w_lds[tid * NUM];
        const float* ql = &q_lds[tid * NUM];
        float prod0 = 1.0f, prod1 = 1.0f;
        #pragma unroll
        for (int k = 0; k < NUM; ++k) {
            const float z = 10.0f * __builtin_fmaf(xv[k], wl[k], -ql[k]);
            const float a = fast_atan(z);
            const float term = __builtin_fmaf(a, 0.31830988618379067f, 1.1f);
            if (k & 1) prod1 *= term; else prod0 *= term;
        }
        // prod in (~0.6^25, ~1.6^25): fp32-safe, single log.
        out[o] = __logf(prod0 * prod1);
    }
}

extern "C" void kernel_launch(void* const* d_in, const int* in_sizes, int n_in,
                              void* d_out, int out_size, void* d_ws, size_t ws_size,
                              hipStream_t stream) {
    const float* x = (const float*)d_in[0];
    const float* w = (const float*)d_in[1];
    const float* q = (const float*)d_in[2];
    float* out = (float*)d_out;

    const int grid = (NOUT + OPB - 1) / OPB;   // 4505 blocks
    dendrite_kernel<<<grid, OPB, 0, stream>>>(x, w, q, out);
}